// Round 17
// baseline (879.723 us; speedup 1.0000x reference)
//
#include <hip/hip_runtime.h>
#include <cstdint>
#include <cstddef>

#define N_NODES 100000
#define N_EDGES 400000
#define N_GRAPHS 4096
#define DF 196      // P*d
#define DD 49
#define NPB 5       // nodes per block in agg kernel
#define TST 200     // padded row stride (shorts) for split buffers
#define ESTF 116    // conv epilogue LDS row stride (floats)

#define AS1 __attribute__((address_space(1)))
#define AS3 __attribute__((address_space(3)))

typedef __bf16 bf16x8 __attribute__((ext_vector_type(8)));
typedef float f32x4 __attribute__((ext_vector_type(4)));

__device__ __forceinline__ unsigned short f2bf(float f) {
  unsigned int u = __float_as_uint(f);
  u = u + 0x7FFFu + ((u >> 16) & 1u);   // RNE
  return (unsigned short)(u >> 16);
}
__device__ __forceinline__ float bf2f(unsigned short h) {
  return __uint_as_float(((unsigned int)h) << 16);
}

// ---------------- fused conv weight build: PHM sum + fragment pack + split ----
__global__ void convert_wfrag_kernel(const float* __restrict__ cA,
                                     const float* __restrict__ cW,
                                     unsigned short* __restrict__ wfrag) {
  int idx = blockIdx.x * blockDim.x + threadIdx.x;
  if (idx >= 3 * 100352) return;
  int l = idx / 100352;
  int r = idx - l * 100352;
  int ct = r / 7168; int r1 = r - ct * 7168;
  int ks = r1 / 1024; int r2 = r1 - ks * 1024;
  int h = r2 / 512;  int r3 = r2 - h * 512;
  int ln = r3 / 8;   int j = r3 - ln * 8;
  int col = ct * 16 + (ln & 15);
  int k = ks * 32 + (ln >> 4) * 8 + j;
  float v = 0.f;
  if (col < DF && k < DF) {
    int k4 = k / DD, p = k - (k / DD) * DD;
    int j4 = col / DD, q = col - (col / DD) * DD;
#pragma unroll
    for (int i = 0; i < 4; i++)
      v += cA[((l * 4 + i) * 4 + k4) * 4 + j4] * cW[((l * 4 + i) * DD + p) * DD + q];
  }
  unsigned short hi = f2bf(v);
  wfrag[idx] = (h == 0) ? hi : f2bf(v - bf2f(hi));
}

// ---------------- merged small setup: LUT + gate(frag) + gbias + downstream --
__global__ void setup_small_kernel(const float* __restrict__ bond, float* __restrict__ lut,
                                   const float* __restrict__ pA, const float* __restrict__ pW,
                                   const float* __restrict__ pb, const float* __restrict__ rtw,
                                   const float* __restrict__ rtb,
                                   unsigned short* __restrict__ wfragG,
                                   float* __restrict__ gbias,
                                   const float* __restrict__ dnA,
                                   const float* __restrict__ W1, const float* __restrict__ W2,
                                   const float* __restrict__ W3,
                                   float* __restrict__ M1, float* __restrict__ M2,
                                   float* __restrict__ M3) {
  int idx0 = blockIdx.x * blockDim.x + threadIdx.x;
  const int NL = 3 * 512 * DF;          // 301056
  const int NGF = 28672;                // gate frag: 4ct x 7ks x 2h x 64 x 8
  const int NB2 = 64;                   // gbias (49 used)
  const int n1 = DF * 256, n2 = 256 * 128, n3 = 128 * 4;
  if (idx0 < NL) {
    int idx = idx0;
    int l = idx / (512 * DF);
    int r = idx - l * (512 * DF);
    int code = r / DF, c = r - (r / DF) * DF;
    int a0 = code & 7, a1 = (code >> 3) & 7, a2 = (code >> 6) & 7;
    lut[idx] = bond[((l * 3 + 0) * 8 + a0) * DF + c]
             + bond[((l * 3 + 1) * 8 + a1) * DF + c]
             + bond[((l * 3 + 2) * 8 + a2) * DF + c];
  } else if (idx0 < NL + NGF) {
    int idx = idx0 - NL;
    int ct = idx / 7168; int r1 = idx - ct * 7168;
    int ks = r1 / 1024; int r2 = r1 - ks * 1024;
    int h = r2 / 512;  int r3 = r2 - h * 512;
    int ln = r3 / 8;   int j = r3 - ln * 8;
    int col = ct * 16 + (ln & 15);
    int k = ks * 32 + (ln >> 4) * 8 + j;
    float v = 0.f;
    if (col < DD && k < DF) {
      int kp = k / DD, p = k - (k / DD) * DD;
#pragma unroll
      for (int i = 0; i < 4; i++) {
        float aw = 0.f;
#pragma unroll
        for (int j4 = 0; j4 < 4; j4++) aw += pA[(i * 4 + kp) * 4 + j4] * rtw[j4];
        v += aw * pW[(i * DD + p) * DD + col];
      }
    }
    unsigned short hi = f2bf(v);
    wfragG[idx] = (h == 0) ? hi : f2bf(v - bf2f(hi));
  } else if (idx0 < NL + NGF + NB2) {
    int q = idx0 - NL - NGF;
    if (q < DD) {
      float s = rtb[q];
#pragma unroll
      for (int j = 0; j < 4; j++) s += rtw[j] * pb[j * DD + q];
      gbias[q] = s;
    }
  } else if (idx0 < NL + NGF + NB2 + n1 + n2 + n3) {
    int idx = idx0 - NL - NGF - NB2;
    if (idx < n1) {
      int r = idx >> 8, c = idx & 255;
      int k = r / DD, p = r - (r / DD) * DD;
      int j = c >> 6, Q = c & 63;
      float s = 0.f;
#pragma unroll
      for (int i = 0; i < 4; i++) s += dnA[i * 16 + k * 4 + j] * W1[(i * DD + p) * 64 + Q];
      M1[idx] = s;
    } else if (idx < n1 + n2) {
      int m = idx - n1;
      int r = m >> 7, c = m & 127;
      int k = r >> 6, p = r & 63, j = c >> 5, q = c & 31;
      float s = 0.f;
#pragma unroll
      for (int i = 0; i < 4; i++) s += dnA[64 + i * 16 + k * 4 + j] * W2[(i * 64 + p) * 32 + q];
      M2[m] = s;
    } else {
      int m = idx - n1 - n2;
      int r = m >> 2, j = m & 3;
      int k = r >> 5, p = r & 31;
      float s = 0.f;
#pragma unroll
      for (int i = 0; i < 4; i++) s += dnA[128 + i * 16 + k * 4 + j] * W3[i * 32 + p];
      M3[m] = s;
    }
  }
}

// ---------------- CSR build ----------------
__global__ void hist_kernel(const int* __restrict__ dst, int* __restrict__ counts) {
  int e = blockIdx.x * blockDim.x + threadIdx.x;
  if (e < N_EDGES) atomicAdd(&counts[dst[e]], 1);
}

__global__ void scan_local_kernel(const int* __restrict__ counts, int* __restrict__ offs,
                                  int* __restrict__ bsum) {
  __shared__ int sm[256];
  int tid = threadIdx.x;
  int gid = blockIdx.x * 256 + tid;
  int v = (gid < N_NODES) ? counts[gid] : 0;
  sm[tid] = v;
  __syncthreads();
  for (int d = 1; d < 256; d <<= 1) {
    int add = (tid >= d) ? sm[tid - d] : 0;
    __syncthreads();
    sm[tid] += add;
    __syncthreads();
  }
  if (gid < N_NODES) offs[gid] = sm[tid] - v;
  if (tid == 255) bsum[blockIdx.x] = sm[255];
}

__global__ void scan_bsum_kernel(int* __restrict__ bsum, int* __restrict__ bpre, int nb) {
  __shared__ int sm[512];
  int tid = threadIdx.x;
  int v = (tid < nb) ? bsum[tid] : 0;
  sm[tid] = v;
  __syncthreads();
  for (int d = 1; d < 512; d <<= 1) {
    int add = (tid >= d) ? sm[tid - d] : 0;
    __syncthreads();
    sm[tid] += add;
    __syncthreads();
  }
  if (tid < nb) bpre[tid] = sm[tid] - v;
}

__global__ void add_off_kernel(int* __restrict__ offs, const int* __restrict__ bpre) {
  int gid = blockIdx.x * blockDim.x + threadIdx.x;
  if (gid < N_NODES) offs[gid] += bpre[gid >> 8];
  if (gid == 0) offs[N_NODES] = N_EDGES;
}

__global__ void scatter_kernel(const int* __restrict__ src, const int* __restrict__ dst,
                               const int* __restrict__ ea, int* __restrict__ counts,
                               const int* __restrict__ offs,
                               unsigned int* __restrict__ sorted) {
  int e = blockIdx.x * blockDim.x + threadIdx.x;
  if (e >= N_EDGES) return;
  int d = dst[e];
  int code = ea[e * 3 + 0] | (ea[e * 3 + 1] << 3) | (ea[e * 3 + 2] << 6);
  int pos = offs[d] + atomicSub(&counts[d], 1) - 1;
  sorted[pos] = (unsigned int)src[e] | ((unsigned int)code << 17);
}

__global__ void sortseg_kernel(const int* __restrict__ offs,
                               unsigned int* __restrict__ sorted) {
  int n = blockIdx.x * blockDim.x + threadIdx.x;
  if (n >= N_NODES) return;
  int s = offs[n], e = offs[n + 1];
  for (int i = s + 1; i < e; i++) {
    unsigned int v = sorted[i];
    int j = i - 1;
    while (j >= s && sorted[j] > v) { sorted[j + 1] = sorted[j]; j--; }
    sorted[j + 1] = v;
  }
}

// ---------------- atom encoder ----------------
__global__ void atom_enc_kernel(const int* __restrict__ x, const float* __restrict__ emb,
                                float* __restrict__ h0) {
  int idx = blockIdx.x * blockDim.x + threadIdx.x;
  if (idx >= N_NODES * DF) return;
  int n = idx / DF;
  int c = idx - n * DF;
  float s = 0.f;
#pragma unroll
  for (int f = 0; f < 9; f++) {
    int xi = x[n * 9 + f];
    s += emb[(f * 119 + xi) * DF + c];
  }
  h0[idx] = s;
}

// ---------------- CSR aggregation -> split bf16 hi/lo output ----------------
__global__ __launch_bounds__(256)
void agg_kernel(const float* __restrict__ h, const int* __restrict__ offs,
                const unsigned int* __restrict__ sorted, const float* __restrict__ lut,
                unsigned short* __restrict__ tH, unsigned short* __restrict__ tL) {
  int t = threadIdx.x;
  int i = t / 49, q = t - i * 49;
  if (i >= NPB) return;
  int node = blockIdx.x * NPB + i;
  if (node >= N_NODES) return;
  const float4* h4 = (const float4*)h;
  const float4* l4 = (const float4*)lut;
  float4 acc = h4[(size_t)node * 49 + q];
  int s = offs[node], e = offs[node + 1];
  int k = s;
  for (; k + 2 <= e; k += 2) {
    unsigned int se0 = sorted[k];
    unsigned int se1 = sorted[k + 1];
    int s0 = se0 & 0x1FFFF, c0 = se0 >> 17;
    int s1 = se1 & 0x1FFFF, c1 = se1 >> 17;
    float4 hv0 = h4[(size_t)s0 * 49 + q];
    float4 lv0 = l4[(size_t)c0 * 49 + q];
    float4 hv1 = h4[(size_t)s1 * 49 + q];
    float4 lv1 = l4[(size_t)c1 * 49 + q];
    acc.x += (hv0.x + lv0.x) + (hv1.x + lv1.x);
    acc.y += (hv0.y + lv0.y) + (hv1.y + lv1.y);
    acc.z += (hv0.z + lv0.z) + (hv1.z + lv1.z);
    acc.w += (hv0.w + lv0.w) + (hv1.w + lv1.w);
  }
  if (k < e) {
    unsigned int se = sorted[k];
    int srcn = se & 0x1FFFF;
    int code = se >> 17;
    float4 hv = h4[(size_t)srcn * 49 + q];
    float4 lv = l4[(size_t)code * 49 + q];
    acc.x += hv.x + lv.x;
    acc.y += hv.y + lv.y;
    acc.z += hv.z + lv.z;
    acc.w += hv.w + lv.w;
  }
  ushort4 hh, ll;
  hh.x = f2bf(acc.x); ll.x = f2bf(acc.x - bf2f(hh.x));
  hh.y = f2bf(acc.y); ll.y = f2bf(acc.y - bf2f(hh.y));
  hh.z = f2bf(acc.z); ll.z = f2bf(acc.z - bf2f(hh.z));
  hh.w = f2bf(acc.w); ll.w = f2bf(acc.w - bf2f(hh.w));
  size_t ob = (size_t)node * TST + q * 4;
  *(ushort4*)(tH + ob) = hh;
  *(ushort4*)(tL + ob) = ll;
  if (q == 48) {   // zero the 4 padding shorts (elements 196..199)
    ushort4 z = make_ushort4(0, 0, 0, 0);
    *(ushort4*)(tH + (size_t)node * TST + 196) = z;
    *(ushort4*)(tL + (size_t)node * TST + 196) = z;
  }
}

// ---------------- conv GEMM: column-split MFMA, fp32 output, LDS diet -------
// Block = 128 rows x 7 col-tiles (ch = blockIdx&1). acc[2][7] = 56 AGPR.
// W SINGLE-buffered (14336 B); per phase: COMPUTE -> lgkm barrier -> WLOAD
// next -> counted-vmcnt barrier (4 newest A-loads stay in flight). Epilogue:
// 4 quarters of 32 rows, fp32 LDS transpose [32][116] = 14848 B. LDS total
// 14848 B -> 4 blocks/CU (VGPR 80 allows 4 waves/SIMD) regardless of the
// scheduler's effective LDS window. Conv is PURE-READ on tH/tL; writes fp32
// z into zout (=h, free at conv time).
__global__ __launch_bounds__(256, 2)
void conv_mfma_kernel(const unsigned short* __restrict__ tH,
                      const unsigned short* __restrict__ tL,
                      const unsigned short* __restrict__ wfrag,
                      const float* __restrict__ bias,
                      float* __restrict__ zout,
                      float* __restrict__ stats) {
  __shared__ __align__(16) unsigned short smW[7424];   // 14848 B
  const int t = threadIdx.x;
  const int lane = t & 63;
  const int w = t >> 6;
  const int li = lane & 15;
  const int rg = lane >> 4;
  const int rb = blockIdx.x >> 1;
  const int ch = blockIdx.x & 1;
  const int rowbase = rb * 128 + w * 32;
  const unsigned short* wsrc = wfrag + (size_t)ch * 7 * 7168;  // ct-major

  f32x4 acc[2][7];
#pragma unroll
  for (int rt = 0; rt < 2; rt++)
#pragma unroll
    for (int ct = 0; ct < 7; ct++) acc[rt][ct] = (f32x4){0.f, 0.f, 0.f, 0.f};

  uint4 b0h[2], b0l[2], b1h[2], b1l[2], b2h[2], b2l[2], b3h[2], b3l[2];

#define LOADA(ks, aH, aL)                                                      \
  {                                                                            \
    _Pragma("unroll") for (int rt = 0; rt < 2; rt++) {                         \
      size_t o = (size_t)(rowbase + rt * 16 + li) * TST + (ks) * 32 + rg * 8;  \
      aH[rt] = *(const uint4*)(tH + o);                                        \
      aL[rt] = *(const uint4*)(tL + o);                                        \
    }                                                                          \
  }

// async W stage into the single slot: 14 chunks (7ct x 2h) over 4 waves.
#define WLOAD(ks)                                                              \
  {                                                                            \
    _Pragma("unroll") for (int f0 = 0; f0 < 4; f0++) {                         \
      int g = f0 * 4 + w;                                                      \
      if (g < 14) {                                                            \
        int hh = g & 1, ct = g >> 1;                                           \
        __builtin_amdgcn_global_load_lds(                                      \
            (AS1 const void*)(wsrc + ((size_t)(ct * 7 + (ks)) * 2 + hh) * 512 + lane * 8), \
            (AS3 void*)(smW + (ct * 2 + hh) * 512), 16, 0, 0);                 \
      }                                                                        \
    }                                                                          \
  }

#define COMPUTE(aH, aL)                                                        \
  {                                                                            \
    _Pragma("unroll") for (int ct = 0; ct < 7; ct++) {                         \
      bf16x8 bh = *(const bf16x8*)(smW + ((ct * 2 + 0) * 512 + lane * 8));     \
      bf16x8 bl = *(const bf16x8*)(smW + ((ct * 2 + 1) * 512 + lane * 8));     \
      _Pragma("unroll") for (int rt = 0; rt < 2; rt++) {                       \
        bf16x8 ah = *(const bf16x8*)&aH[rt];                                   \
        bf16x8 al = *(const bf16x8*)&aL[rt];                                   \
        acc[rt][ct] = __builtin_amdgcn_mfma_f32_16x16x32_bf16(ah, bh, acc[rt][ct], 0, 0, 0); \
        acc[rt][ct] = __builtin_amdgcn_mfma_f32_16x16x32_bf16(al, bh, acc[rt][ct], 0, 0, 0); \
        acc[rt][ct] = __builtin_amdgcn_mfma_f32_16x16x32_bf16(ah, bl, acc[rt][ct], 0, 0, 0); \
      }                                                                        \
    }                                                                          \
  }

#define BARW(N)                                                                \
  {                                                                            \
    asm volatile("s_waitcnt vmcnt(" #N ")" ::: "memory");                      \
    __builtin_amdgcn_s_barrier();                                              \
  }
#define BARL()                                                                 \
  {                                                                            \
    asm volatile("s_waitcnt lgkmcnt(0)" ::: "memory");                         \
    __builtin_amdgcn_s_barrier();                                              \
  }
#define PINW() __builtin_amdgcn_sched_barrier(0)

  WLOAD(0);
  PINW();
  LOADA(0, b0h, b0l);
  LOADA(1, b1h, b1l);
  LOADA(2, b2h, b2l);
  BARW(12);                                   // W0 ready; 12 A-loads in flight
  COMPUTE(b0h, b0l);                          // ks0
  BARL();
  WLOAD(1); PINW(); LOADA(3, b3h, b3l); BARW(4);
  COMPUTE(b1h, b1l);                          // ks1
  BARL();
  WLOAD(2); PINW(); LOADA(4, b0h, b0l); BARW(4);
  COMPUTE(b2h, b2l);                          // ks2
  BARL();
  WLOAD(3); PINW(); LOADA(5, b1h, b1l); BARW(4);
  COMPUTE(b3h, b3l);                          // ks3
  BARL();
  WLOAD(4); PINW(); LOADA(6, b2h, b2l); BARW(4);
  COMPUTE(b0h, b0l);                          // ks4
  BARL();
  WLOAD(5); PINW(); BARW(0);
  COMPUTE(b1h, b1l);                          // ks5
  BARL();
  WLOAD(6); PINW(); BARW(0);
  COMPUTE(b2h, b2l);                          // ks6

  // ---- epilogue: 4 quarters of 32 rows, fp32 LDS transpose -> float4 stores -
  float part[7], psq[7];
#pragma unroll
  for (int ct = 0; ct < 7; ct++) { part[ct] = 0.f; psq[ct] = 0.f; }

  float* lz = (float*)smW;                 // [32][ESTF]
  const int NU = ch ? 21 : 28;             // float4 per row (84 / 112 floats)

#pragma unroll
  for (int qt = 0; qt < 4; qt++) {
    __syncthreads();
    if (w == qt) {
#pragma unroll
      for (int ct = 0; ct < 7; ct++) {
        int cl = ct * 16 + li;
        int cg = ch * 112 + cl;
        float bv = (cg < DF) ? bias[cg] : 0.f;
#pragma unroll
        for (int rt = 0; rt < 2; rt++) {
#pragma unroll
          for (int r = 0; r < 4; r++) {
            int row = rt * 16 + rg * 4 + r;            // 0..31
            int gr = rowbase + rt * 16 + rg * 4 + r;
            float y = acc[rt][ct][r] + bv;
            if (gr < N_NODES && cg < DF) { part[ct] += y; psq[ct] += y * y; }
            lz[row * ESTF + cl] = y;
          }
        }
      }
    }
    __syncthreads();
    for (int idx = t; idx < 32 * NU; idx += 256) {
      int row = idx / NU, u = idx - (idx / NU) * NU;
      int gr = rb * 128 + qt * 32 + row;
      if (gr < N_NODES) {
        float4 v = *(const float4*)(lz + row * ESTF + u * 4);
        *(float4*)(zout + (size_t)gr * DF + ch * 112 + u * 4) = v;
      }
    }
  }

  // ---- stats reduction ----
  __syncthreads();
  float* redS = (float*)smW;     // [4][112]
  float* redQ = redS + 4 * 112;  // [4][112]
#pragma unroll
  for (int ct = 0; ct < 7; ct++) {
    float p = part[ct], q = psq[ct];
    p += __shfl_xor(p, 16, 64); p += __shfl_xor(p, 32, 64);
    q += __shfl_xor(q, 16, 64); q += __shfl_xor(q, 32, 64);
    if (rg == 0) { redS[w * 112 + ct * 16 + li] = p; redQ[w * 112 + ct * 16 + li] = q; }
  }
  __syncthreads();
  if (t < 112) {
    int cg = ch * 112 + t;
    if (cg < DF) {
      float s1 = redS[t] + redS[112 + t] + redS[224 + t] + redS[336 + t];
      float s2 = redQ[t] + redQ[112 + t] + redQ[224 + t] + redQ[336 + t];
      atomicAdd(&stats[cg], s1);
      atomicAdd(&stats[DF + cg], s2);
    }
  }
#undef LOADA
#undef WLOAD
#undef COMPUTE
#undef BARW
#undef BARL
#undef PINW
}

// ---------------- batch-norm + relu + skip (z in h, in place) ----------------
__global__ void bn_relu_split_kernel(const float* __restrict__ stats,
                                     const float* __restrict__ gamma,
                                     const float* __restrict__ beta,
                                     const float* __restrict__ h0,
                                     float* __restrict__ h,
                                     unsigned short* __restrict__ tH,
                                     unsigned short* __restrict__ tL,
                                     int write_split) {
  int idx = blockIdx.x * blockDim.x + threadIdx.x;
  if (idx >= N_NODES * DD) return;
  int n = idx / DD, q = idx - (idx / DD) * DD;
  size_t fb = (size_t)n * DF + q * 4;
  float4 zv = *(const float4*)(h + fb);
  float4 sk = *(const float4*)(h0 + fb);
  int c = q * 4;
  const float invN = 1.f / N_NODES;
  float4 o;
  {
    float mu = stats[c + 0] * invN;
    float var = stats[DF + c + 0] * invN - mu * mu;
    o.x = fmaxf((zv.x - mu) * rsqrtf(var + 1e-5f) * gamma[c + 0] + beta[c + 0], 0.f) + sk.x;
  }
  {
    float mu = stats[c + 1] * invN;
    float var = stats[DF + c + 1] * invN - mu * mu;
    o.y = fmaxf((zv.y - mu) * rsqrtf(var + 1e-5f) * gamma[c + 1] + beta[c + 1], 0.f) + sk.y;
  }
  {
    float mu = stats[c + 2] * invN;
    float var = stats[DF + c + 2] * invN - mu * mu;
    o.z = fmaxf((zv.z - mu) * rsqrtf(var + 1e-5f) * gamma[c + 2] + beta[c + 2], 0.f) + sk.z;
  }
  {
    float mu = stats[c + 3] * invN;
    float var = stats[DF + c + 3] * invN - mu * mu;
    o.w = fmaxf((zv.w - mu) * rsqrtf(var + 1e-5f) * gamma[c + 3] + beta[c + 3], 0.f) + sk.w;
  }
  *(float4*)(h + fb) = o;
  if (write_split) {
    size_t ib = (size_t)n * TST + q * 4;
    ushort4 sh, sl;
    sh.x = f2bf(o.x); sl.x = f2bf(o.x - bf2f(sh.x));
    sh.y = f2bf(o.y); sl.y = f2bf(o.y - bf2f(sh.y));
    sh.z = f2bf(o.z); sl.z = f2bf(o.z - bf2f(sh.z));
    sh.w = f2bf(o.w); sl.w = f2bf(o.w - bf2f(sh.w));
    *(ushort4*)(tH + ib) = sh;
    *(ushort4*)(tL + ib) = sl;
  }
}

// ---------------- gate via MFMA: g = sigmoid(split(h) @ Wg + gb) ------------
__global__ __launch_bounds__(256, 2)
void gate_mfma_kernel(const unsigned short* __restrict__ tH,
                      const unsigned short* __restrict__ tL,
                      const unsigned short* __restrict__ wfragG,
                      const float* __restrict__ gbias,
                      float* __restrict__ g) {
  __shared__ __align__(16) unsigned short smW[28672];  // [ct4][ks7][h2][lane64][j8]
  const int t = threadIdx.x;
  const int lane = t & 63;
  const int w = t >> 6;
  const int li = lane & 15;
  const int rg = lane >> 4;
  const int rowbase = blockIdx.x * 128 + w * 32;

  f32x4 acc[2][4];
#pragma unroll
  for (int rt = 0; rt < 2; rt++)
#pragma unroll
    for (int ct = 0; ct < 4; ct++) acc[rt][ct] = (f32x4){0.f, 0.f, 0.f, 0.f};

  uint4 b0h[2], b0l[2], b1h[2], b1l[2], b2h[2], b2l[2], b3h[2], b3l[2];

#define LOADA(ks, aH, aL)                                                      \
  {                                                                            \
    _Pragma("unroll") for (int rt = 0; rt < 2; rt++) {                         \
      size_t o = (size_t)(rowbase + rt * 16 + li) * TST + (ks) * 32 + rg * 8;  \
      aH[rt] = *(const uint4*)(tH + o);                                        \
      aL[rt] = *(const uint4*)(tL + o);                                        \
    }                                                                          \
  }

#define COMPUTE(ks, aH, aL)                                                    \
  {                                                                            \
    _Pragma("unroll") for (int ct = 0; ct < 4; ct++) {                         \
      bf16x8 bh = *(const bf16x8*)(smW + ((ct * 7 + (ks)) * 2 + 0) * 512 + lane * 8); \
      bf16x8 bl = *(const bf16x8*)(smW + ((ct * 7 + (ks)) * 2 + 1) * 512 + lane * 8); \
      _Pragma("unroll") for (int rt = 0; rt < 2; rt++) {                       \
        bf16x8 ah = *(const bf16x8*)&aH[rt];                                   \
        bf16x8 al = *(const bf16x8*)&aL[rt];                                   \
        acc[rt][ct] = __builtin_amdgcn_mfma_f32_16x16x32_bf16(ah, bh, acc[rt][ct], 0, 0, 0); \
        acc[rt][ct] = __builtin_amdgcn_mfma_f32_16x16x32_bf16(al, bh, acc[rt][ct], 0, 0, 0); \
        acc[rt][ct] = __builtin_amdgcn_mfma_f32_16x16x32_bf16(ah, bl, acc[rt][ct], 0, 0, 0); \
      }                                                                        \
    }                                                                          \
  }

  LOADA(0, b0h, b0l);
  LOADA(1, b1h, b1l);
  LOADA(2, b2h, b2l);
  for (int i = t; i < 3584; i += 256)
    *(uint4*)(smW + (size_t)i * 8) = *(const uint4*)(wfragG + (size_t)i * 8);
  __syncthreads();
  LOADA(3, b3h, b3l); COMPUTE(0, b0h, b0l);
  LOADA(4, b0h, b0l); COMPUTE(1, b1h, b1l);
  LOADA(5, b1h, b1l); COMPUTE(2, b2h, b2l);
  LOADA(6, b2h, b2l); COMPUTE(3, b3h, b3l);
  COMPUTE(4, b0h, b0l);
  COMPUTE(5, b1h, b1l);
  COMPUTE(6, b2h, b2l);

#pragma unroll
  for (int ct = 0; ct < 4; ct++) {
    int c = ct * 16 + li;
    if (c < DD) {
      float bv = gbias[c];
#pragma unroll
      for (int rt = 0; rt < 2; rt++) {
#pragma unroll
        for (int r = 0; r < 4; r++) {
          int gr = rowbase + rt * 16 + rg * 4 + r;
          if (gr < N_NODES) {
            float v = acc[rt][ct][r] + bv;
            g[(size_t)gr * DD + c] = 1.f / (1.f + __expf(-v));
          }
        }
      }
    }
  }
#undef LOADA
#undef COMPUTE
}

// ---------------- fp32 GEMM (downstream) ----------------
template<int S, int MODE>
__launch_bounds__(256)
__global__ void gemm_kernel(const float* X, const float* __restrict__ W,
                            const float* __restrict__ bias, float* Y,
                            float* __restrict__ stats, int Nrows, int K, int NC) {
  constexpr int WN = S * 64;
  __shared__ __align__(16) float At[32][64];
  __shared__ __align__(16) float Wl[32][WN];
  const int t = threadIdx.x;
  const int tx = t & 15;
  const int ty = t >> 4;
  const int r0 = blockIdx.x * 64;

  float acc[S][4][4];
#pragma unroll
  for (int s = 0; s < S; s++)
#pragma unroll
    for (int i = 0; i < 4; i++)
#pragma unroll
      for (int j = 0; j < 4; j++) acc[s][i][j] = 0.f;

  const int lr = t >> 2;
  const int kb = (t & 3) * 8;
  constexpr int TPR = S * 16;
  const int cw = (t % TPR) * 4;
  const int kr = t / TPR;
  constexpr int RPP = 256 / TPR;
  constexpr int PASSES = 32 / RPP;

  for (int k0 = 0; k0 < K; k0 += 32) {
    {
      const int gr = r0 + lr;
      const float* xp = X + (size_t)gr * K + k0 + kb;
      if (gr < Nrows && (k0 + kb + 7) < K) {
        float4 v0 = *(const float4*)(xp);
        float4 v1 = *(const float4*)(xp + 4);
        At[kb + 0][lr] = v0.x; At[kb + 1][lr] = v0.y;
        At[kb + 2][lr] = v0.z; At[kb + 3][lr] = v0.w;
        At[kb + 4][lr] = v1.x; At[kb + 5][lr] = v1.y;
        At[kb + 6][lr] = v1.z; At[kb + 7][lr] = v1.w;
      } else {
#pragma unroll
        for (int i = 0; i < 8; i++) {
          int kk = kb + i;
          float v = 0.f;
          if (gr < Nrows && (k0 + kk) < K) v = xp[i];
          At[kk][lr] = v;
        }
      }
    }
#pragma unroll
    for (int ps = 0; ps < PASSES; ps++) {
      int kk = kr + ps * RPP;
      int gk = k0 + kk;
      if (gk < K && (cw + 3) < NC && ((NC & 3) == 0)) {
        float4 v = *(const float4*)(W + (size_t)gk * NC + cw);
        Wl[kk][cw + 0] = v.x; Wl[kk][cw + 1] = v.y;
        Wl[kk][cw + 2] = v.z; Wl[kk][cw + 3] = v.w;
      } else {
#pragma unroll
        for (int j = 0; j < 4; j++) {
          int c = cw + j;
          float v = 0.f;
          if (gk < K && c < NC) v = W[(size_t)gk * NC + c];
          Wl[kk][c] = v;
        }
      }
    }
    __syncthreads();
#pragma unroll 4
    for (int kk = 0; kk < 32; kk++) {
      float4 a = *(const float4*)&At[kk][ty * 4];
      float av[4] = {a.x, a.y, a.z, a.w};
#pragma unroll
      for (int s = 0; s < S; s++) {
        float4 w = *(const float4*)&Wl[kk][s * 64 + tx * 4];
        float wv[4] = {w.x, w.y, w.z, w.w};
#pragma unroll
        for (int i = 0; i < 4; i++)
#pragma unroll
          for (int j = 0; j < 4; j++)
            acc[s][i][j] = fmaf(av[i], wv[j], acc[s][i][j]);
      }
    }
    __syncthreads();
  }

#pragma unroll
  for (int s = 0; s < S; s++)
#pragma unroll
    for (int j = 0; j < 4; j++) {
      int c = s * 64 + tx * 4 + j;
      float bv = (c < NC) ? bias[c] : 0.f;
#pragma unroll
      for (int i = 0; i < 4; i++) {
        float y = acc[s][i][j] + bv;
        if (MODE == 1) y = 1.f / (1.f + __expf(-y));
        acc[s][i][j] = y;
      }
    }
#pragma unroll
  for (int i = 0; i < 4; i++) {
    int gr = r0 + ty * 4 + i;
    if (gr < Nrows) {
#pragma unroll
      for (int s = 0; s < S; s++)
#pragma unroll
        for (int j = 0; j < 4; j++) {
          int c = s * 64 + tx * 4 + j;
          if (c < NC) Y[(size_t)gr * NC + c] = acc[s][i][j];
        }
    }
  }
  if (MODE == 0) {
    float* red = &Wl[0][0];
    __syncthreads();
#pragma unroll
    for (int s = 0; s < S; s++)
#pragma unroll
      for (int j = 0; j < 4; j++) {
        float p = 0.f;
#pragma unroll
        for (int i = 0; i < 4; i++)
          if ((r0 + ty * 4 + i) < Nrows) p += acc[s][i][j];
        red[ty * WN + s * 64 + tx * 4 + j] = p;
      }
    __syncthreads();
    if (t < WN) {
      float tot = 0.f;
#pragma unroll
      for (int yy = 0; yy < 16; yy++) tot += red[yy * WN + t];
      if (t < NC) atomicAdd(&stats[t], tot);
    }
    __syncthreads();
#pragma unroll
    for (int s = 0; s < S; s++)
#pragma unroll
      for (int j = 0; j < 4; j++) {
        float p = 0.f;
#pragma unroll
        for (int i = 0; i < 4; i++)
          if ((r0 + ty * 4 + i) < Nrows) p += acc[s][i][j] * acc[s][i][j];
        red[ty * WN + s * 64 + tx * 4 + j] = p;
      }
    __syncthreads();
    if (t < WN) {
      float tot = 0.f;
#pragma unroll
      for (int yy = 0; yy < 16; yy++) tot += red[yy * WN + t];
      if (t < NC) atomicAdd(&stats[NC + t], tot);
    }
  }
}

// ---------------- batch-norm + relu (fp32 input, downstream) ----------------
__global__ void bn_relu_kernel(const float* __restrict__ z, const float* __restrict__ stats,
                               const float* __restrict__ gamma, const float* __restrict__ beta,
                               float* __restrict__ out,
                               int total, int NC, float invN) {
  int idx = blockIdx.x * blockDim.x + threadIdx.x;
  if (idx >= total) return;
  int c = idx % NC;
  float mu = stats[c] * invN;
  float var = stats[NC + c] * invN - mu * mu;
  float v = (z[idx] - mu) * rsqrtf(var + 1e-5f) * gamma[c] + beta[c];
  out[idx] = fmaxf(v, 0.f);
}

// ---------------- pooling ----------------
__device__ __forceinline__ int lower_bound_dev(const int* a, int n, int v) {
  int lo = 0, hi = n;
  while (lo < hi) { int mid = (lo + hi) >> 1; if (a[mid] < v) lo = mid + 1; else hi = mid; }
  return lo;
}

__global__ void pool_kernel(const float* __restrict__ h, const float* __restrict__ g,
                            const int* __restrict__ batch, float* __restrict__ pooled) {
  int b = blockIdx.x;
  __shared__ int bounds[2];
  if (threadIdx.x == 0) {
    bounds[0] = lower_bound_dev(batch, N_NODES, b);
    bounds[1] = lower_bound_dev(batch, N_NODES, b + 1);
  }
  __syncthreads();
  int c = threadIdx.x;
  if (c >= DF) return;
  int s = bounds[0], e = bounds[1];
  int q = c % DD;
  float acc = 0.f;
  for (int n = s; n < e; n++)
    acc = fmaf(h[(size_t)n * DF + c], g[(size_t)n * DD + q], acc);
  pooled[(size_t)b * DF + c] = acc;
}

// ---------------- final ----------------
__global__ void final_kernel(const float* __restrict__ z2, const float* __restrict__ M3,
                             const float* __restrict__ b3, const float* __restrict__ rtw,
                             const float* __restrict__ rtb, float* __restrict__ out) {
  __shared__ float sM[128 * 4];
  __shared__ float srw[4];
  __shared__ float srb;
  int t = threadIdx.x;
  for (int i = t; i < 512; i += 256) sM[i] = M3[i];
  if (t < 4) srw[t] = rtw[t];
  if (t == 4) srb = rtb[0];
  __syncthreads();
  int b = blockIdx.x * blockDim.x + t;
  if (b >= N_GRAPHS) return;
  float o0 = b3[0], o1 = b3[1], o2 = b3[2], o3 = b3[3];
  const float* zp = z2 + (size_t)b * 128;
  for (int p = 0; p < 128; p++) {
    float v = zp[p];
    o0 = fmaf(v, sM[p * 4 + 0], o0);
    o1 = fmaf(v, sM[p * 4 + 1], o1);
    o2 = fmaf(v, sM[p * 4 + 2], o2);
    o3 = fmaf(v, sM[p * 4 + 3], o3);
  }
  out[b] = srb + o0 * srw[0] + o1 * srw[1] + o2 * srw[2] + o3 * srw[3];
}

// ---------------- launch ----------------
extern "C" void kernel_launch(void* const* d_in, const int* in_sizes, int n_in,
                              void* d_out, int out_size, void* d_ws, size_t ws_size,
                              hipStream_t stream) {
  (void)in_sizes; (void)n_in; (void)out_size; (void)ws_size;
  const int* x          = (const int*)d_in[0];
  const int* edge_index = (const int*)d_in[1];
  const int* edge_attr  = (const int*)d_in[2];
  const int* batch      = (const int*)d_in[3];
  const float* atom_emb = (const float*)d_in[4];
  const float* bond_emb = (const float*)d_in[5];
  const float* conv_A   = (const float*)d_in[6];
  const float* conv_W   = (const float*)d_in[7];
  const float* conv_b   = (const float*)d_in[8];
  const float* mp_gamma = (const float*)d_in[9];
  const float* mp_beta  = (const float*)d_in[10];
  const float* pool_A   = (const float*)d_in[11];
  const float* pool_W   = (const float*)d_in[12];
  const float* pool_b   = (const float*)d_in[13];
  const float* pool_rt_w = (const float*)d_in[14];
  const float* pool_rt_b = (const float*)d_in[15];
  const float* dn_A     = (const float*)d_in[16];
  const float* dn1_W    = (const float*)d_in[17];
  const float* dn1_b    = (const float*)d_in[18];
  const float* dn1_gamma = (const float*)d_in[19];
  const float* dn1_beta = (const float*)d_in[20];
  const float* dn2_W    = (const float*)d_in[21];
  const float* dn2_b    = (const float*)d_in[22];
  const float* dn2_gamma = (const float*)d_in[23];
  const float* dn2_beta = (const float*)d_in[24];
  const float* dn3_W    = (const float*)d_in[25];
  const float* dn3_b    = (const float*)d_in[26];
  const float* rt_w     = (const float*)d_in[27];
  const float* rt_b     = (const float*)d_in[28];
  float* out = (float*)d_out;

  char* ws = (char*)d_ws;
  size_t off = 0;
  auto alloc = [&](size_t bytes) -> char* {
    char* p = ws + off;
    off = (off + bytes + 255) & ~(size_t)255;
    return p;
  };
  const size_t HBYTES = (size_t)N_NODES * DF * sizeof(float);
  float* h0 = (float*)alloc(HBYTES);
  float* h  = (float*)alloc(HBYTES);
  unsigned short* tH = (unsigned short*)alloc((size_t)N_NODES * TST * 2 + 4096);
  unsigned short* tL = (unsigned short*)alloc((size_t)N_NODES * TST * 2 + 4096);
  // post-MP buffers carved from h0 (dead after the last bn_relu_split's skip
  // read; h0 fully rewritten by atom_enc each call). They must NOT alias
  // tH/tL (gate reads them) nor h (pool reads h).
  float* g      = (float*)h0;
  float* pooled = (float*)((char*)h0 + (((size_t)N_NODES * DD * 4 + 255) & ~(size_t)255));
  float* z1     = (float*)((char*)pooled + (((size_t)N_GRAPHS * DF * 4 + 255) & ~(size_t)255));
  float* z2     = (float*)((char*)z1 + (((size_t)N_GRAPHS * 256 * 4 + 255) & ~(size_t)255));
  unsigned short* wfrag = (unsigned short*)alloc((size_t)3 * 100352 * 2);
  unsigned short* wfragG = (unsigned short*)alloc((size_t)28672 * 2);
  float* gbias  = (float*)alloc(64 * 4);
  float* M1     = (float*)alloc(DF * 256 * 4);
  float* M2     = (float*)alloc(256 * 128 * 4);
  float* M3     = (float*)alloc(128 * 4 * 4);
  float* stats  = (float*)alloc(2048 * 4);
  int*  counts  = (int*)alloc(N_NODES * 4);
  int*  offs    = (int*)alloc((N_NODES + 1) * 4);
  unsigned int* sorted = (unsigned int*)alloc((size_t)N_EDGES * 4);
  float* lut    = (float*)alloc((size_t)3 * 512 * DF * 4);
  int*  bsum    = (int*)alloc(512 * 4);
  int*  bpre    = (int*)alloc(512 * 4);

  const int* src = edge_index;
  const int* dst = edge_index + N_EDGES;
  const int NB = (N_NODES + 255) / 256;

  hipMemsetAsync(stats, 0, 2048 * 4, stream);
  hipMemsetAsync(counts, 0, N_NODES * 4, stream);

  convert_wfrag_kernel<<<(3 * 100352 + 255) / 256, 256, 0, stream>>>(conv_A, conv_W, wfrag);
  {
    const int total = 3 * 512 * DF + 28672 + 64 + (DF * 256 + 256 * 128 + 128 * 4);
    setup_small_kernel<<<(total + 255) / 256, 256, 0, stream>>>(
        bond_emb, lut, pool_A, pool_W, pool_b, pool_rt_w, pool_rt_b, wfragG, gbias,
        dn_A, dn1_W, dn2_W, dn3_W, M1, M2, M3);
  }

  hist_kernel<<<(N_EDGES + 255) / 256, 256, 0, stream>>>(dst, counts);
  scan_local_kernel<<<NB, 256, 0, stream>>>(counts, offs, bsum);
  scan_bsum_kernel<<<1, 512, 0, stream>>>(bsum, bpre, NB);
  add_off_kernel<<<NB, 256, 0, stream>>>(offs, bpre);
  scatter_kernel<<<(N_EDGES + 255) / 256, 256, 0, stream>>>(
      src, dst, edge_attr, counts, offs, sorted);
  sortseg_kernel<<<NB, 256, 0, stream>>>(offs, sorted);

  atom_enc_kernel<<<(N_NODES * DF + 255) / 256, 256, 0, stream>>>(x, atom_emb, h0);

  const int NROW = (N_NODES + 127) / 128;      // 782
  const int NCONV = NROW * 2;                  // column-split: 1564 blocks
  for (int l = 0; l < 3; l++) {
    const float* hl = (l == 0) ? h0 : h;
    agg_kernel<<<(N_NODES + NPB - 1) / NPB, 256, 0, stream>>>(
        hl, offs, sorted, lut + (size_t)l * 512 * DF, tH, tL);
    float* st = stats + l * 392;
    conv_mfma_kernel<<<NCONV, 256, 0, stream>>>(
        tH, tL, wfrag + (size_t)l * 100352, conv_b + (size_t)l * DF, h, st);
    bn_relu_split_kernel<<<(N_NODES * DD + 255) / 256, 256, 0, stream>>>(
        st, mp_gamma + l * DF, mp_beta + l * DF, h0, h, tH, tL, (l == 2) ? 1 : 0);
  }

  gate_mfma_kernel<<<NROW, 256, 0, stream>>>(tH, tL, wfragG, gbias, g);
  pool_kernel<<<N_GRAPHS, 256, 0, stream>>>(h, g, batch, pooled);

  gemm_kernel<4, 0><<<(N_GRAPHS + 63) / 64, 256, 0, stream>>>(
      pooled, M1, dn1_b, z1, stats + 1176, N_GRAPHS, DF, 256);
  bn_relu_kernel<<<(N_GRAPHS * 256 + 255) / 256, 256, 0, stream>>>(
      z1, stats + 1176, dn1_gamma, dn1_beta, z1, N_GRAPHS * 256, 256, 1.f / N_GRAPHS);
  gemm_kernel<2, 0><<<(N_GRAPHS + 63) / 64, 256, 0, stream>>>(
      z1, M2, dn2_b, z2, stats + 1688, N_GRAPHS, 256, 128);
  bn_relu_kernel<<<(N_GRAPHS * 128 + 255) / 256, 256, 0, stream>>>(
      z2, stats + 1688, dn2_gamma, dn2_beta, z2, N_GRAPHS * 128, 128, 1.f / N_GRAPHS);
  final_kernel<<<(N_GRAPHS + 255) / 256, 256, 0, stream>>>(z2, M3, dn3_b, rt_w, rt_b, out);
}

// Round 18
// 828.307 us; speedup vs baseline: 1.0621x; 1.0621x over previous
//
#include <hip/hip_runtime.h>
#include <cstdint>
#include <cstddef>

#define N_NODES 100000
#define N_EDGES 400000
#define N_GRAPHS 4096
#define DF 196      // P*d
#define DD 49
#define NPB 5       // nodes per block in agg kernel
#define TST 200     // padded row stride (shorts) for split buffers
#define WSLOT2 7168 // shorts per W LDS slot (7 ct x 2 h x 512)
#define ESTF 116    // conv epilogue LDS row stride (floats)

#define AS1 __attribute__((address_space(1)))
#define AS3 __attribute__((address_space(3)))

typedef __bf16 bf16x8 __attribute__((ext_vector_type(8)));
typedef float f32x4 __attribute__((ext_vector_type(4)));

__device__ __forceinline__ unsigned short f2bf(float f) {
  unsigned int u = __float_as_uint(f);
  u = u + 0x7FFFu + ((u >> 16) & 1u);   // RNE
  return (unsigned short)(u >> 16);
}
__device__ __forceinline__ float bf2f(unsigned short h) {
  return __uint_as_float(((unsigned int)h) << 16);
}

// ---------------- fused conv weight build: PHM sum + fragment pack + split ----
__global__ void convert_wfrag_kernel(const float* __restrict__ cA,
                                     const float* __restrict__ cW,
                                     unsigned short* __restrict__ wfrag) {
  int idx = blockIdx.x * blockDim.x + threadIdx.x;
  if (idx >= 3 * 100352) return;
  int l = idx / 100352;
  int r = idx - l * 100352;
  int ct = r / 7168; int r1 = r - ct * 7168;
  int ks = r1 / 1024; int r2 = r1 - ks * 1024;
  int h = r2 / 512;  int r3 = r2 - h * 512;
  int ln = r3 / 8;   int j = r3 - ln * 8;
  int col = ct * 16 + (ln & 15);
  int k = ks * 32 + (ln >> 4) * 8 + j;
  float v = 0.f;
  if (col < DF && k < DF) {
    int k4 = k / DD, p = k - (k / DD) * DD;
    int j4 = col / DD, q = col - (col / DD) * DD;
#pragma unroll
    for (int i = 0; i < 4; i++)
      v += cA[((l * 4 + i) * 4 + k4) * 4 + j4] * cW[((l * 4 + i) * DD + p) * DD + q];
  }
  unsigned short hi = f2bf(v);
  wfrag[idx] = (h == 0) ? hi : f2bf(v - bf2f(hi));
}

// ---------------- merged small setup: LUT + gate(frag) + gbias + downstream --
__global__ void setup_small_kernel(const float* __restrict__ bond, float* __restrict__ lut,
                                   const float* __restrict__ pA, const float* __restrict__ pW,
                                   const float* __restrict__ pb, const float* __restrict__ rtw,
                                   const float* __restrict__ rtb,
                                   unsigned short* __restrict__ wfragG,
                                   float* __restrict__ gbias,
                                   const float* __restrict__ dnA,
                                   const float* __restrict__ W1, const float* __restrict__ W2,
                                   const float* __restrict__ W3,
                                   float* __restrict__ M1, float* __restrict__ M2,
                                   float* __restrict__ M3) {
  int idx0 = blockIdx.x * blockDim.x + threadIdx.x;
  const int NL = 3 * 512 * DF;          // 301056
  const int NGF = 28672;                // gate frag: 4ct x 7ks x 2h x 64 x 8
  const int NB2 = 64;                   // gbias (49 used)
  const int n1 = DF * 256, n2 = 256 * 128, n3 = 128 * 4;
  if (idx0 < NL) {
    int idx = idx0;
    int l = idx / (512 * DF);
    int r = idx - l * (512 * DF);
    int code = r / DF, c = r - (r / DF) * DF;
    int a0 = code & 7, a1 = (code >> 3) & 7, a2 = (code >> 6) & 7;
    lut[idx] = bond[((l * 3 + 0) * 8 + a0) * DF + c]
             + bond[((l * 3 + 1) * 8 + a1) * DF + c]
             + bond[((l * 3 + 2) * 8 + a2) * DF + c];
  } else if (idx0 < NL + NGF) {
    int idx = idx0 - NL;
    int ct = idx / 7168; int r1 = idx - ct * 7168;
    int ks = r1 / 1024; int r2 = r1 - ks * 1024;
    int h = r2 / 512;  int r3 = r2 - h * 512;
    int ln = r3 / 8;   int j = r3 - ln * 8;
    int col = ct * 16 + (ln & 15);
    int k = ks * 32 + (ln >> 4) * 8 + j;
    float v = 0.f;
    if (col < DD && k < DF) {
      int kp = k / DD, p = k - (k / DD) * DD;
#pragma unroll
      for (int i = 0; i < 4; i++) {
        float aw = 0.f;
#pragma unroll
        for (int j4 = 0; j4 < 4; j4++) aw += pA[(i * 4 + kp) * 4 + j4] * rtw[j4];
        v += aw * pW[(i * DD + p) * DD + col];
      }
    }
    unsigned short hi = f2bf(v);
    wfragG[idx] = (h == 0) ? hi : f2bf(v - bf2f(hi));
  } else if (idx0 < NL + NGF + NB2) {
    int q = idx0 - NL - NGF;
    if (q < DD) {
      float s = rtb[q];
#pragma unroll
      for (int j = 0; j < 4; j++) s += rtw[j] * pb[j * DD + q];
      gbias[q] = s;
    }
  } else if (idx0 < NL + NGF + NB2 + n1 + n2 + n3) {
    int idx = idx0 - NL - NGF - NB2;
    if (idx < n1) {
      int r = idx >> 8, c = idx & 255;
      int k = r / DD, p = r - (r / DD) * DD;
      int j = c >> 6, Q = c & 63;
      float s = 0.f;
#pragma unroll
      for (int i = 0; i < 4; i++) s += dnA[i * 16 + k * 4 + j] * W1[(i * DD + p) * 64 + Q];
      M1[idx] = s;
    } else if (idx < n1 + n2) {
      int m = idx - n1;
      int r = m >> 7, c = m & 127;
      int k = r >> 6, p = r & 63, j = c >> 5, q = c & 31;
      float s = 0.f;
#pragma unroll
      for (int i = 0; i < 4; i++) s += dnA[64 + i * 16 + k * 4 + j] * W2[(i * 64 + p) * 32 + q];
      M2[m] = s;
    } else {
      int m = idx - n1 - n2;
      int r = m >> 2, j = m & 3;
      int k = r >> 5, p = r & 31;
      float s = 0.f;
#pragma unroll
      for (int i = 0; i < 4; i++) s += dnA[128 + i * 16 + k * 4 + j] * W3[i * 32 + p];
      M3[m] = s;
    }
  }
}

// ---------------- CSR build ----------------
__global__ void hist_kernel(const int* __restrict__ dst, int* __restrict__ counts) {
  int e = blockIdx.x * blockDim.x + threadIdx.x;
  if (e < N_EDGES) atomicAdd(&counts[dst[e]], 1);
}

__global__ void scan_local_kernel(const int* __restrict__ counts, int* __restrict__ offs,
                                  int* __restrict__ bsum) {
  __shared__ int sm[256];
  int tid = threadIdx.x;
  int gid = blockIdx.x * 256 + tid;
  int v = (gid < N_NODES) ? counts[gid] : 0;
  sm[tid] = v;
  __syncthreads();
  for (int d = 1; d < 256; d <<= 1) {
    int add = (tid >= d) ? sm[tid - d] : 0;
    __syncthreads();
    sm[tid] += add;
    __syncthreads();
  }
  if (gid < N_NODES) offs[gid] = sm[tid] - v;
  if (tid == 255) bsum[blockIdx.x] = sm[255];
}

__global__ void scan_bsum_kernel(int* __restrict__ bsum, int* __restrict__ bpre, int nb) {
  __shared__ int sm[512];
  int tid = threadIdx.x;
  int v = (tid < nb) ? bsum[tid] : 0;
  sm[tid] = v;
  __syncthreads();
  for (int d = 1; d < 512; d <<= 1) {
    int add = (tid >= d) ? sm[tid - d] : 0;
    __syncthreads();
    sm[tid] += add;
    __syncthreads();
  }
  if (tid < nb) bpre[tid] = sm[tid] - v;
}

__global__ void add_off_kernel(int* __restrict__ offs, const int* __restrict__ bpre) {
  int gid = blockIdx.x * blockDim.x + threadIdx.x;
  if (gid < N_NODES) offs[gid] += bpre[gid >> 8];
  if (gid == 0) offs[N_NODES] = N_EDGES;
}

__global__ void scatter_kernel(const int* __restrict__ src, const int* __restrict__ dst,
                               const int* __restrict__ ea, int* __restrict__ counts,
                               const int* __restrict__ offs,
                               unsigned int* __restrict__ sorted) {
  int e = blockIdx.x * blockDim.x + threadIdx.x;
  if (e >= N_EDGES) return;
  int d = dst[e];
  int code = ea[e * 3 + 0] | (ea[e * 3 + 1] << 3) | (ea[e * 3 + 2] << 6);
  int pos = offs[d] + atomicSub(&counts[d], 1) - 1;
  sorted[pos] = (unsigned int)src[e] | ((unsigned int)code << 17);
}

__global__ void sortseg_kernel(const int* __restrict__ offs,
                               unsigned int* __restrict__ sorted) {
  int n = blockIdx.x * blockDim.x + threadIdx.x;
  if (n >= N_NODES) return;
  int s = offs[n], e = offs[n + 1];
  for (int i = s + 1; i < e; i++) {
    unsigned int v = sorted[i];
    int j = i - 1;
    while (j >= s && sorted[j] > v) { sorted[j + 1] = sorted[j]; j--; }
    sorted[j + 1] = v;
  }
}

// ---------------- atom encoder ----------------
__global__ void atom_enc_kernel(const int* __restrict__ x, const float* __restrict__ emb,
                                float* __restrict__ h0) {
  int idx = blockIdx.x * blockDim.x + threadIdx.x;
  if (idx >= N_NODES * DF) return;
  int n = idx / DF;
  int c = idx - n * DF;
  float s = 0.f;
#pragma unroll
  for (int f = 0; f < 9; f++) {
    int xi = x[n * 9 + f];
    s += emb[(f * 119 + xi) * DF + c];
  }
  h0[idx] = s;
}

// ---------------- CSR aggregation -> split bf16 hi/lo output ----------------
__global__ __launch_bounds__(256)
void agg_kernel(const float* __restrict__ h, const int* __restrict__ offs,
                const unsigned int* __restrict__ sorted, const float* __restrict__ lut,
                unsigned short* __restrict__ tH, unsigned short* __restrict__ tL) {
  int t = threadIdx.x;
  int i = t / 49, q = t - i * 49;
  if (i >= NPB) return;
  int node = blockIdx.x * NPB + i;
  if (node >= N_NODES) return;
  const float4* h4 = (const float4*)h;
  const float4* l4 = (const float4*)lut;
  float4 acc = h4[(size_t)node * 49 + q];
  int s = offs[node], e = offs[node + 1];
  int k = s;
  for (; k + 2 <= e; k += 2) {
    unsigned int se0 = sorted[k];
    unsigned int se1 = sorted[k + 1];
    int s0 = se0 & 0x1FFFF, c0 = se0 >> 17;
    int s1 = se1 & 0x1FFFF, c1 = se1 >> 17;
    float4 hv0 = h4[(size_t)s0 * 49 + q];
    float4 lv0 = l4[(size_t)c0 * 49 + q];
    float4 hv1 = h4[(size_t)s1 * 49 + q];
    float4 lv1 = l4[(size_t)c1 * 49 + q];
    acc.x += (hv0.x + lv0.x) + (hv1.x + lv1.x);
    acc.y += (hv0.y + lv0.y) + (hv1.y + lv1.y);
    acc.z += (hv0.z + lv0.z) + (hv1.z + lv1.z);
    acc.w += (hv0.w + lv0.w) + (hv1.w + lv1.w);
  }
  if (k < e) {
    unsigned int se = sorted[k];
    int srcn = se & 0x1FFFF;
    int code = se >> 17;
    float4 hv = h4[(size_t)srcn * 49 + q];
    float4 lv = l4[(size_t)code * 49 + q];
    acc.x += hv.x + lv.x;
    acc.y += hv.y + lv.y;
    acc.z += hv.z + lv.z;
    acc.w += hv.w + lv.w;
  }
  ushort4 hh, ll;
  hh.x = f2bf(acc.x); ll.x = f2bf(acc.x - bf2f(hh.x));
  hh.y = f2bf(acc.y); ll.y = f2bf(acc.y - bf2f(hh.y));
  hh.z = f2bf(acc.z); ll.z = f2bf(acc.z - bf2f(hh.z));
  hh.w = f2bf(acc.w); ll.w = f2bf(acc.w - bf2f(hh.w));
  size_t ob = (size_t)node * TST + q * 4;
  *(ushort4*)(tH + ob) = hh;
  *(ushort4*)(tL + ob) = ll;
  if (q == 48) {   // zero the 4 padding shorts (elements 196..199)
    ushort4 z = make_ushort4(0, 0, 0, 0);
    *(ushort4*)(tH + (size_t)node * TST + 196) = z;
    *(ushort4*)(tL + (size_t)node * TST + 196) = z;
  }
}

// ---------------- conv GEMM: column-split MFMA (round-16 best) --------------
// Block = 128 rows x 7 col-tiles. acc[2][7] = 56 AGPR -> ~136 total regs.
// W double-buffered via global_load_lds; counted vmcnt(4) barriers keep each
// phase's 4 A-loads in flight. XCD-PAIRED block mapping: the two col-halves
// of the same row-block get blockIdx differing by 8, so they land on the
// same XCD (round-robin mod 8) and the second half's A-read hits that XCD's
// L2 instead of HBM. Conv is PURE-READ on tH/tL; writes fp32 z into zout.
__global__ __launch_bounds__(256, 2)
void conv_mfma_kernel(const unsigned short* __restrict__ tH,
                      const unsigned short* __restrict__ tL,
                      const unsigned short* __restrict__ wfrag,
                      const float* __restrict__ bias,
                      float* __restrict__ zout,
                      float* __restrict__ stats) {
  __shared__ __align__(16) unsigned short smW[14848];  // 29696 B
  const int t = threadIdx.x;
  const int lane = t & 63;
  const int w = t >> 6;
  const int li = lane & 15;
  const int rg = lane >> 4;
  // XCD-paired bijective remap: groups of 16 = 8 row-blocks x 2 halves.
  int rb, ch;
  {
    int b = blockIdx.x;
    if (b < 1552) { int gg = b >> 4, r = b & 15; rb = gg * 8 + (r & 7); ch = r >> 3; }
    else          { int r = b - 1552;            rb = 776 + (r % 6);    ch = r / 6;  }
  }
  const int rowbase = rb * 128 + w * 32;
  const unsigned short* wsrc = wfrag + (size_t)ch * 7 * 7168;  // ct-major

  f32x4 acc[2][7];
#pragma unroll
  for (int rt = 0; rt < 2; rt++)
#pragma unroll
    for (int ct = 0; ct < 7; ct++) acc[rt][ct] = (f32x4){0.f, 0.f, 0.f, 0.f};

  uint4 b0h[2], b0l[2], b1h[2], b1l[2], b2h[2], b2l[2], b3h[2], b3l[2];

#define LOADA(ks, aH, aL)                                                      \
  {                                                                            \
    _Pragma("unroll") for (int rt = 0; rt < 2; rt++) {                         \
      size_t o = (size_t)(rowbase + rt * 16 + li) * TST + (ks) * 32 + rg * 8;  \
      aH[rt] = *(const uint4*)(tH + o);                                        \
      aL[rt] = *(const uint4*)(tL + o);                                        \
    }                                                                          \
  }

// async W stage: 14 chunks (7ct x 2h) over 4 waves (waves 0,1: 4; 2,3: 3).
#define WLOAD(ks, sbase)                                                       \
  {                                                                            \
    _Pragma("unroll") for (int f0 = 0; f0 < 4; f0++) {                         \
      int g = f0 * 4 + w;                                                      \
      if (g < 14) {                                                            \
        int hh = g & 1, ct = g >> 1;                                           \
        __builtin_amdgcn_global_load_lds(                                      \
            (AS1 const void*)(wsrc + ((size_t)(ct * 7 + (ks)) * 2 + hh) * 512 + lane * 8), \
            (AS3 void*)(smW + (sbase) + (ct * 2 + hh) * 512), 16, 0, 0);       \
      }                                                                        \
    }                                                                          \
  }

#define COMPUTE(sbase, aH, aL)                                                 \
  {                                                                            \
    _Pragma("unroll") for (int ct = 0; ct < 7; ct++) {                         \
      bf16x8 bh = *(const bf16x8*)(smW + (sbase) + ((ct * 2 + 0) * 512 + lane * 8)); \
      bf16x8 bl = *(const bf16x8*)(smW + (sbase) + ((ct * 2 + 1) * 512 + lane * 8)); \
      _Pragma("unroll") for (int rt = 0; rt < 2; rt++) {                       \
        bf16x8 ah = *(const bf16x8*)&aH[rt];                                   \
        bf16x8 al = *(const bf16x8*)&aL[rt];                                   \
        acc[rt][ct] = __builtin_amdgcn_mfma_f32_16x16x32_bf16(ah, bh, acc[rt][ct], 0, 0, 0); \
        acc[rt][ct] = __builtin_amdgcn_mfma_f32_16x16x32_bf16(al, bh, acc[rt][ct], 0, 0, 0); \
        acc[rt][ct] = __builtin_amdgcn_mfma_f32_16x16x32_bf16(ah, bl, acc[rt][ct], 0, 0, 0); \
      }                                                                        \
    }                                                                          \
  }

#define BARC(N)                                                                \
  {                                                                            \
    asm volatile("s_waitcnt vmcnt(" #N ")" ::: "memory");                      \
    __builtin_amdgcn_s_barrier();                                              \
  }
#define PINW() __builtin_amdgcn_sched_barrier(0)

  WLOAD(0, 0);
  PINW();
  LOADA(0, b0h, b0l);
  LOADA(1, b1h, b1l);
  LOADA(2, b2h, b2l);
  BARC(12);
  WLOAD(1, WSLOT2); PINW(); LOADA(3, b3h, b3l); COMPUTE(0, b0h, b0l);      BARC(4);  // ks0
  WLOAD(2, 0);      PINW(); LOADA(4, b0h, b0l); COMPUTE(WSLOT2, b1h, b1l); BARC(4);  // ks1
  WLOAD(3, WSLOT2); PINW(); LOADA(5, b1h, b1l); COMPUTE(0, b2h, b2l);      BARC(4);  // ks2
  WLOAD(4, 0);      PINW(); LOADA(6, b2h, b2l); COMPUTE(WSLOT2, b3h, b3l); BARC(4);  // ks3
  WLOAD(5, WSLOT2); PINW();                     COMPUTE(0, b0h, b0l);      BARC(0);  // ks4
  WLOAD(6, 0);      PINW();                     COMPUTE(WSLOT2, b1h, b1l); BARC(0);  // ks5
  COMPUTE(0, b2h, b2l);                                                              // ks6

  // ---- epilogue: per-half fp32 LDS transpose -> coalesced float4 stores -----
  float part[7], psq[7];
#pragma unroll
  for (int ct = 0; ct < 7; ct++) { part[ct] = 0.f; psq[ct] = 0.f; }

  float* lz = (float*)smW;                 // [64][ESTF]
  const int NU = ch ? 21 : 28;             // float4 per row (84 / 112 floats)

#pragma unroll
  for (int half = 0; half < 2; half++) {
    __syncthreads();
    if ((w >> 1) == half) {
      int rl0 = (w & 1) * 32;
#pragma unroll
      for (int ct = 0; ct < 7; ct++) {
        int cl = ct * 16 + li;
        int cg = ch * 112 + cl;
        float bv = (cg < DF) ? bias[cg] : 0.f;
#pragma unroll
        for (int rt = 0; rt < 2; rt++) {
#pragma unroll
          for (int r = 0; r < 4; r++) {
            int row = rl0 + rt * 16 + rg * 4 + r;
            int gr = rowbase + rt * 16 + rg * 4 + r;
            float y = acc[rt][ct][r] + bv;
            if (gr < N_NODES && cg < DF) { part[ct] += y; psq[ct] += y * y; }
            lz[row * ESTF + cl] = y;
          }
        }
      }
    }
    __syncthreads();
    for (int idx = t; idx < 64 * NU; idx += 256) {
      int row = idx / NU, u = idx - (idx / NU) * NU;
      int gr = rb * 128 + half * 64 + row;
      if (gr < N_NODES) {
        float4 v = *(const float4*)(lz + row * ESTF + u * 4);
        *(float4*)(zout + (size_t)gr * DF + ch * 112 + u * 4) = v;
      }
    }
  }

  // ---- stats reduction ----
  __syncthreads();
  float* redS = (float*)smW;     // [4][112]
  float* redQ = redS + 4 * 112;  // [4][112]
#pragma unroll
  for (int ct = 0; ct < 7; ct++) {
    float p = part[ct], q = psq[ct];
    p += __shfl_xor(p, 16, 64); p += __shfl_xor(p, 32, 64);
    q += __shfl_xor(q, 16, 64); q += __shfl_xor(q, 32, 64);
    if (rg == 0) { redS[w * 112 + ct * 16 + li] = p; redQ[w * 112 + ct * 16 + li] = q; }
  }
  __syncthreads();
  if (t < 112) {
    int cg = ch * 112 + t;
    if (cg < DF) {
      float s1 = redS[t] + redS[112 + t] + redS[224 + t] + redS[336 + t];
      float s2 = redQ[t] + redQ[112 + t] + redQ[224 + t] + redQ[336 + t];
      atomicAdd(&stats[cg], s1);
      atomicAdd(&stats[DF + cg], s2);
    }
  }
#undef LOADA
#undef WLOAD
#undef COMPUTE
#undef BARC
#undef PINW
}

// ---------------- batch-norm + relu + skip (z in h, in place) ----------------
__global__ void bn_relu_split_kernel(const float* __restrict__ stats,
                                     const float* __restrict__ gamma,
                                     const float* __restrict__ beta,
                                     const float* __restrict__ h0,
                                     float* __restrict__ h,
                                     unsigned short* __restrict__ tH,
                                     unsigned short* __restrict__ tL,
                                     int write_split) {
  int idx = blockIdx.x * blockDim.x + threadIdx.x;
  if (idx >= N_NODES * DD) return;
  int n = idx / DD, q = idx - (idx / DD) * DD;
  size_t fb = (size_t)n * DF + q * 4;
  float4 zv = *(const float4*)(h + fb);
  float4 sk = *(const float4*)(h0 + fb);
  int c = q * 4;
  const float invN = 1.f / N_NODES;
  float4 o;
  {
    float mu = stats[c + 0] * invN;
    float var = stats[DF + c + 0] * invN - mu * mu;
    o.x = fmaxf((zv.x - mu) * rsqrtf(var + 1e-5f) * gamma[c + 0] + beta[c + 0], 0.f) + sk.x;
  }
  {
    float mu = stats[c + 1] * invN;
    float var = stats[DF + c + 1] * invN - mu * mu;
    o.y = fmaxf((zv.y - mu) * rsqrtf(var + 1e-5f) * gamma[c + 1] + beta[c + 1], 0.f) + sk.y;
  }
  {
    float mu = stats[c + 2] * invN;
    float var = stats[DF + c + 2] * invN - mu * mu;
    o.z = fmaxf((zv.z - mu) * rsqrtf(var + 1e-5f) * gamma[c + 2] + beta[c + 2], 0.f) + sk.z;
  }
  {
    float mu = stats[c + 3] * invN;
    float var = stats[DF + c + 3] * invN - mu * mu;
    o.w = fmaxf((zv.w - mu) * rsqrtf(var + 1e-5f) * gamma[c + 3] + beta[c + 3], 0.f) + sk.w;
  }
  *(float4*)(h + fb) = o;
  if (write_split) {
    size_t ib = (size_t)n * TST + q * 4;
    ushort4 sh, sl;
    sh.x = f2bf(o.x); sl.x = f2bf(o.x - bf2f(sh.x));
    sh.y = f2bf(o.y); sl.y = f2bf(o.y - bf2f(sh.y));
    sh.z = f2bf(o.z); sl.z = f2bf(o.z - bf2f(sh.z));
    sh.w = f2bf(o.w); sl.w = f2bf(o.w - bf2f(sh.w));
    *(ushort4*)(tH + ib) = sh;
    *(ushort4*)(tL + ib) = sl;
  }
}

// ---------------- gate via MFMA: g = sigmoid(split(h) @ Wg + gb) ------------
__global__ __launch_bounds__(256, 2)
void gate_mfma_kernel(const unsigned short* __restrict__ tH,
                      const unsigned short* __restrict__ tL,
                      const unsigned short* __restrict__ wfragG,
                      const float* __restrict__ gbias,
                      float* __restrict__ g) {
  __shared__ __align__(16) unsigned short smW[28672];  // [ct4][ks7][h2][lane64][j8]
  const int t = threadIdx.x;
  const int lane = t & 63;
  const int w = t >> 6;
  const int li = lane & 15;
  const int rg = lane >> 4;
  const int rowbase = blockIdx.x * 128 + w * 32;

  f32x4 acc[2][4];
#pragma unroll
  for (int rt = 0; rt < 2; rt++)
#pragma unroll
    for (int ct = 0; ct < 4; ct++) acc[rt][ct] = (f32x4){0.f, 0.f, 0.f, 0.f};

  uint4 b0h[2], b0l[2], b1h[2], b1l[2], b2h[2], b2l[2], b3h[2], b3l[2];

#define LOADA(ks, aH, aL)                                                      \
  {                                                                            \
    _Pragma("unroll") for (int rt = 0; rt < 2; rt++) {                         \
      size_t o = (size_t)(rowbase + rt * 16 + li) * TST + (ks) * 32 + rg * 8;  \
      aH[rt] = *(const uint4*)(tH + o);                                        \
      aL[rt] = *(const uint4*)(tL + o);                                        \
    }                                                                          \
  }

#define COMPUTE(ks, aH, aL)                                                    \
  {                                                                            \
    _Pragma("unroll") for (int ct = 0; ct < 4; ct++) {                         \
      bf16x8 bh = *(const bf16x8*)(smW + ((ct * 7 + (ks)) * 2 + 0) * 512 + lane * 8); \
      bf16x8 bl = *(const bf16x8*)(smW + ((ct * 7 + (ks)) * 2 + 1) * 512 + lane * 8); \
      _Pragma("unroll") for (int rt = 0; rt < 2; rt++) {                       \
        bf16x8 ah = *(const bf16x8*)&aH[rt];                                   \
        bf16x8 al = *(const bf16x8*)&aL[rt];                                   \
        acc[rt][ct] = __builtin_amdgcn_mfma_f32_16x16x32_bf16(ah, bh, acc[rt][ct], 0, 0, 0); \
        acc[rt][ct] = __builtin_amdgcn_mfma_f32_16x16x32_bf16(al, bh, acc[rt][ct], 0, 0, 0); \
        acc[rt][ct] = __builtin_amdgcn_mfma_f32_16x16x32_bf16(ah, bl, acc[rt][ct], 0, 0, 0); \
      }                                                                        \
    }                                                                          \
  }

  LOADA(0, b0h, b0l);
  LOADA(1, b1h, b1l);
  LOADA(2, b2h, b2l);
  for (int i = t; i < 3584; i += 256)
    *(uint4*)(smW + (size_t)i * 8) = *(const uint4*)(wfragG + (size_t)i * 8);
  __syncthreads();
  LOADA(3, b3h, b3l); COMPUTE(0, b0h, b0l);
  LOADA(4, b0h, b0l); COMPUTE(1, b1h, b1l);
  LOADA(5, b1h, b1l); COMPUTE(2, b2h, b2l);
  LOADA(6, b2h, b2l); COMPUTE(3, b3h, b3l);
  COMPUTE(4, b0h, b0l);
  COMPUTE(5, b1h, b1l);
  COMPUTE(6, b2h, b2l);

#pragma unroll
  for (int ct = 0; ct < 4; ct++) {
    int c = ct * 16 + li;
    if (c < DD) {
      float bv = gbias[c];
#pragma unroll
      for (int rt = 0; rt < 2; rt++) {
#pragma unroll
        for (int r = 0; r < 4; r++) {
          int gr = rowbase + rt * 16 + rg * 4 + r;
          if (gr < N_NODES) {
            float v = acc[rt][ct][r] + bv;
            g[(size_t)gr * DD + c] = 1.f / (1.f + __expf(-v));
          }
        }
      }
    }
  }
#undef LOADA
#undef COMPUTE
}

// ---------------- fp32 GEMM (downstream) ----------------
template<int S, int MODE>
__launch_bounds__(256)
__global__ void gemm_kernel(const float* X, const float* __restrict__ W,
                            const float* __restrict__ bias, float* Y,
                            float* __restrict__ stats, int Nrows, int K, int NC) {
  constexpr int WN = S * 64;
  __shared__ __align__(16) float At[32][64];
  __shared__ __align__(16) float Wl[32][WN];
  const int t = threadIdx.x;
  const int tx = t & 15;
  const int ty = t >> 4;
  const int r0 = blockIdx.x * 64;

  float acc[S][4][4];
#pragma unroll
  for (int s = 0; s < S; s++)
#pragma unroll
    for (int i = 0; i < 4; i++)
#pragma unroll
      for (int j = 0; j < 4; j++) acc[s][i][j] = 0.f;

  const int lr = t >> 2;
  const int kb = (t & 3) * 8;
  constexpr int TPR = S * 16;
  const int cw = (t % TPR) * 4;
  const int kr = t / TPR;
  constexpr int RPP = 256 / TPR;
  constexpr int PASSES = 32 / RPP;

  for (int k0 = 0; k0 < K; k0 += 32) {
    {
      const int gr = r0 + lr;
      const float* xp = X + (size_t)gr * K + k0 + kb;
      if (gr < Nrows && (k0 + kb + 7) < K) {
        float4 v0 = *(const float4*)(xp);
        float4 v1 = *(const float4*)(xp + 4);
        At[kb + 0][lr] = v0.x; At[kb + 1][lr] = v0.y;
        At[kb + 2][lr] = v0.z; At[kb + 3][lr] = v0.w;
        At[kb + 4][lr] = v1.x; At[kb + 5][lr] = v1.y;
        At[kb + 6][lr] = v1.z; At[kb + 7][lr] = v1.w;
      } else {
#pragma unroll
        for (int i = 0; i < 8; i++) {
          int kk = kb + i;
          float v = 0.f;
          if (gr < Nrows && (k0 + kk) < K) v = xp[i];
          At[kk][lr] = v;
        }
      }
    }
#pragma unroll
    for (int ps = 0; ps < PASSES; ps++) {
      int kk = kr + ps * RPP;
      int gk = k0 + kk;
      if (gk < K && (cw + 3) < NC && ((NC & 3) == 0)) {
        float4 v = *(const float4*)(W + (size_t)gk * NC + cw);
        Wl[kk][cw + 0] = v.x; Wl[kk][cw + 1] = v.y;
        Wl[kk][cw + 2] = v.z; Wl[kk][cw + 3] = v.w;
      } else {
#pragma unroll
        for (int j = 0; j < 4; j++) {
          int c = cw + j;
          float v = 0.f;
          if (gk < K && c < NC) v = W[(size_t)gk * NC + c];
          Wl[kk][c] = v;
        }
      }
    }
    __syncthreads();
#pragma unroll 4
    for (int kk = 0; kk < 32; kk++) {
      float4 a = *(const float4*)&At[kk][ty * 4];
      float av[4] = {a.x, a.y, a.z, a.w};
#pragma unroll
      for (int s = 0; s < S; s++) {
        float4 w = *(const float4*)&Wl[kk][s * 64 + tx * 4];
        float wv[4] = {w.x, w.y, w.z, w.w};
#pragma unroll
        for (int i = 0; i < 4; i++)
#pragma unroll
          for (int j = 0; j < 4; j++)
            acc[s][i][j] = fmaf(av[i], wv[j], acc[s][i][j]);
      }
    }
    __syncthreads();
  }

#pragma unroll
  for (int s = 0; s < S; s++)
#pragma unroll
    for (int j = 0; j < 4; j++) {
      int c = s * 64 + tx * 4 + j;
      float bv = (c < NC) ? bias[c] : 0.f;
#pragma unroll
      for (int i = 0; i < 4; i++) {
        float y = acc[s][i][j] + bv;
        if (MODE == 1) y = 1.f / (1.f + __expf(-y));
        acc[s][i][j] = y;
      }
    }
#pragma unroll
  for (int i = 0; i < 4; i++) {
    int gr = r0 + ty * 4 + i;
    if (gr < Nrows) {
#pragma unroll
      for (int s = 0; s < S; s++)
#pragma unroll
        for (int j = 0; j < 4; j++) {
          int c = s * 64 + tx * 4 + j;
          if (c < NC) Y[(size_t)gr * NC + c] = acc[s][i][j];
        }
    }
  }
  if (MODE == 0) {
    float* red = &Wl[0][0];
    __syncthreads();
#pragma unroll
    for (int s = 0; s < S; s++)
#pragma unroll
      for (int j = 0; j < 4; j++) {
        float p = 0.f;
#pragma unroll
        for (int i = 0; i < 4; i++)
          if ((r0 + ty * 4 + i) < Nrows) p += acc[s][i][j];
        red[ty * WN + s * 64 + tx * 4 + j] = p;
      }
    __syncthreads();
    if (t < WN) {
      float tot = 0.f;
#pragma unroll
      for (int yy = 0; yy < 16; yy++) tot += red[yy * WN + t];
      if (t < NC) atomicAdd(&stats[t], tot);
    }
    __syncthreads();
#pragma unroll
    for (int s = 0; s < S; s++)
#pragma unroll
      for (int j = 0; j < 4; j++) {
        float p = 0.f;
#pragma unroll
        for (int i = 0; i < 4; i++)
          if ((r0 + ty * 4 + i) < Nrows) p += acc[s][i][j] * acc[s][i][j];
        red[ty * WN + s * 64 + tx * 4 + j] = p;
      }
    __syncthreads();
    if (t < WN) {
      float tot = 0.f;
#pragma unroll
      for (int yy = 0; yy < 16; yy++) tot += red[yy * WN + t];
      if (t < NC) atomicAdd(&stats[NC + t], tot);
    }
  }
}

// ---------------- batch-norm + relu (fp32 input, downstream) ----------------
__global__ void bn_relu_kernel(const float* __restrict__ z, const float* __restrict__ stats,
                               const float* __restrict__ gamma, const float* __restrict__ beta,
                               float* __restrict__ out,
                               int total, int NC, float invN) {
  int idx = blockIdx.x * blockDim.x + threadIdx.x;
  if (idx >= total) return;
  int c = idx % NC;
  float mu = stats[c] * invN;
  float var = stats[NC + c] * invN - mu * mu;
  float v = (z[idx] - mu) * rsqrtf(var + 1e-5f) * gamma[c] + beta[c];
  out[idx] = fmaxf(v, 0.f);
}

// ---------------- pooling ----------------
__device__ __forceinline__ int lower_bound_dev(const int* a, int n, int v) {
  int lo = 0, hi = n;
  while (lo < hi) { int mid = (lo + hi) >> 1; if (a[mid] < v) lo = mid + 1; else hi = mid; }
  return lo;
}

__global__ void pool_kernel(const float* __restrict__ h, const float* __restrict__ g,
                            const int* __restrict__ batch, float* __restrict__ pooled) {
  int b = blockIdx.x;
  __shared__ int bounds[2];
  if (threadIdx.x == 0) {
    bounds[0] = lower_bound_dev(batch, N_NODES, b);
    bounds[1] = lower_bound_dev(batch, N_NODES, b + 1);
  }
  __syncthreads();
  int c = threadIdx.x;
  if (c >= DF) return;
  int s = bounds[0], e = bounds[1];
  int q = c % DD;
  float acc = 0.f;
  for (int n = s; n < e; n++)
    acc = fmaf(h[(size_t)n * DF + c], g[(size_t)n * DD + q], acc);
  pooled[(size_t)b * DF + c] = acc;
}

// ---------------- final ----------------
__global__ void final_kernel(const float* __restrict__ z2, const float* __restrict__ M3,
                             const float* __restrict__ b3, const float* __restrict__ rtw,
                             const float* __restrict__ rtb, float* __restrict__ out) {
  __shared__ float sM[128 * 4];
  __shared__ float srw[4];
  __shared__ float srb;
  int t = threadIdx.x;
  for (int i = t; i < 512; i += 256) sM[i] = M3[i];
  if (t < 4) srw[t] = rtw[t];
  if (t == 4) srb = rtb[0];
  __syncthreads();
  int b = blockIdx.x * blockDim.x + t;
  if (b >= N_GRAPHS) return;
  float o0 = b3[0], o1 = b3[1], o2 = b3[2], o3 = b3[3];
  const float* zp = z2 + (size_t)b * 128;
  for (int p = 0; p < 128; p++) {
    float v = zp[p];
    o0 = fmaf(v, sM[p * 4 + 0], o0);
    o1 = fmaf(v, sM[p * 4 + 1], o1);
    o2 = fmaf(v, sM[p * 4 + 2], o2);
    o3 = fmaf(v, sM[p * 4 + 3], o3);
  }
  out[b] = srb + o0 * srw[0] + o1 * srw[1] + o2 * srw[2] + o3 * srw[3];
}

// ---------------- launch ----------------
extern "C" void kernel_launch(void* const* d_in, const int* in_sizes, int n_in,
                              void* d_out, int out_size, void* d_ws, size_t ws_size,
                              hipStream_t stream) {
  (void)in_sizes; (void)n_in; (void)out_size; (void)ws_size;
  const int* x          = (const int*)d_in[0];
  const int* edge_index = (const int*)d_in[1];
  const int* edge_attr  = (const int*)d_in[2];
  const int* batch      = (const int*)d_in[3];
  const float* atom_emb = (const float*)d_in[4];
  const float* bond_emb = (const float*)d_in[5];
  const float* conv_A   = (const float*)d_in[6];
  const float* conv_W   = (const float*)d_in[7];
  const float* conv_b   = (const float*)d_in[8];
  const float* mp_gamma = (const float*)d_in[9];
  const float* mp_beta  = (const float*)d_in[10];
  const float* pool_A   = (const float*)d_in[11];
  const float* pool_W   = (const float*)d_in[12];
  const float* pool_b   = (const float*)d_in[13];
  const float* pool_rt_w = (const float*)d_in[14];
  const float* pool_rt_b = (const float*)d_in[15];
  const float* dn_A     = (const float*)d_in[16];
  const float* dn1_W    = (const float*)d_in[17];
  const float* dn1_b    = (const float*)d_in[18];
  const float* dn1_gamma = (const float*)d_in[19];
  const float* dn1_beta = (const float*)d_in[20];
  const float* dn2_W    = (const float*)d_in[21];
  const float* dn2_b    = (const float*)d_in[22];
  const float* dn2_gamma = (const float*)d_in[23];
  const float* dn2_beta = (const float*)d_in[24];
  const float* dn3_W    = (const float*)d_in[25];
  const float* dn3_b    = (const float*)d_in[26];
  const float* rt_w     = (const float*)d_in[27];
  const float* rt_b     = (const float*)d_in[28];
  float* out = (float*)d_out;

  char* ws = (char*)d_ws;
  size_t off = 0;
  auto alloc = [&](size_t bytes) -> char* {
    char* p = ws + off;
    off = (off + bytes + 255) & ~(size_t)255;
    return p;
  };
  const size_t HBYTES = (size_t)N_NODES * DF * sizeof(float);
  float* h0 = (float*)alloc(HBYTES);
  float* h  = (float*)alloc(HBYTES);
  unsigned short* tH = (unsigned short*)alloc((size_t)N_NODES * TST * 2 + 4096);
  unsigned short* tL = (unsigned short*)alloc((size_t)N_NODES * TST * 2 + 4096);
  // post-MP buffers carved from h0 (dead after the last bn_relu_split's skip
  // read; h0 fully rewritten by atom_enc each call). They must NOT alias
  // tH/tL (gate reads them) nor h (pool reads h).
  float* g      = (float*)h0;
  float* pooled = (float*)((char*)h0 + (((size_t)N_NODES * DD * 4 + 255) & ~(size_t)255));
  float* z1     = (float*)((char*)pooled + (((size_t)N_GRAPHS * DF * 4 + 255) & ~(size_t)255));
  float* z2     = (float*)((char*)z1 + (((size_t)N_GRAPHS * 256 * 4 + 255) & ~(size_t)255));
  unsigned short* wfrag = (unsigned short*)alloc((size_t)3 * 100352 * 2);
  unsigned short* wfragG = (unsigned short*)alloc((size_t)28672 * 2);
  float* gbias  = (float*)alloc(64 * 4);
  float* M1     = (float*)alloc(DF * 256 * 4);
  float* M2     = (float*)alloc(256 * 128 * 4);
  float* M3     = (float*)alloc(128 * 4 * 4);
  float* stats  = (float*)alloc(2048 * 4);
  int*  counts  = (int*)alloc(N_NODES * 4);
  int*  offs    = (int*)alloc((N_NODES + 1) * 4);
  unsigned int* sorted = (unsigned int*)alloc((size_t)N_EDGES * 4);
  float* lut    = (float*)alloc((size_t)3 * 512 * DF * 4);
  int*  bsum    = (int*)alloc(512 * 4);
  int*  bpre    = (int*)alloc(512 * 4);

  const int* src = edge_index;
  const int* dst = edge_index + N_EDGES;
  const int NB = (N_NODES + 255) / 256;

  hipMemsetAsync(stats, 0, 2048 * 4, stream);
  hipMemsetAsync(counts, 0, N_NODES * 4, stream);

  convert_wfrag_kernel<<<(3 * 100352 + 255) / 256, 256, 0, stream>>>(conv_A, conv_W, wfrag);
  {
    const int total = 3 * 512 * DF + 28672 + 64 + (DF * 256 + 256 * 128 + 128 * 4);
    setup_small_kernel<<<(total + 255) / 256, 256, 0, stream>>>(
        bond_emb, lut, pool_A, pool_W, pool_b, pool_rt_w, pool_rt_b, wfragG, gbias,
        dn_A, dn1_W, dn2_W, dn3_W, M1, M2, M3);
  }

  hist_kernel<<<(N_EDGES + 255) / 256, 256, 0, stream>>>(dst, counts);
  scan_local_kernel<<<NB, 256, 0, stream>>>(counts, offs, bsum);
  scan_bsum_kernel<<<1, 512, 0, stream>>>(bsum, bpre, NB);
  add_off_kernel<<<NB, 256, 0, stream>>>(offs, bpre);
  scatter_kernel<<<(N_EDGES + 255) / 256, 256, 0, stream>>>(
      src, dst, edge_attr, counts, offs, sorted);
  sortseg_kernel<<<NB, 256, 0, stream>>>(offs, sorted);

  atom_enc_kernel<<<(N_NODES * DF + 255) / 256, 256, 0, stream>>>(x, atom_emb, h0);

  const int NROW = (N_NODES + 127) / 128;      // 782
  const int NCONV = NROW * 2;                  // column-split: 1564 blocks
  for (int l = 0; l < 3; l++) {
    const float* hl = (l == 0) ? h0 : h;
    agg_kernel<<<(N_NODES + NPB - 1) / NPB, 256, 0, stream>>>(
        hl, offs, sorted, lut + (size_t)l * 512 * DF, tH, tL);
    float* st = stats + l * 392;
    conv_mfma_kernel<<<NCONV, 256, 0, stream>>>(
        tH, tL, wfrag + (size_t)l * 100352, conv_b + (size_t)l * DF, h, st);
    bn_relu_split_kernel<<<(N_NODES * DD + 255) / 256, 256, 0, stream>>>(
        st, mp_gamma + l * DF, mp_beta + l * DF, h0, h, tH, tL, (l == 2) ? 1 : 0);
  }

  gate_mfma_kernel<<<NROW, 256, 0, stream>>>(tH, tL, wfragG, gbias, g);
  pool_kernel<<<N_GRAPHS, 256, 0, stream>>>(h, g, batch, pooled);

  gemm_kernel<4, 0><<<(N_GRAPHS + 63) / 64, 256, 0, stream>>>(
      pooled, M1, dn1_b, z1, stats + 1176, N_GRAPHS, DF, 256);
  bn_relu_kernel<<<(N_GRAPHS * 256 + 255) / 256, 256, 0, stream>>>(
      z1, stats + 1176, dn1_gamma, dn1_beta, z1, N_GRAPHS * 256, 256, 1.f / N_GRAPHS);
  gemm_kernel<2, 0><<<(N_GRAPHS + 63) / 64, 256, 0, stream>>>(
      z1, M2, dn2_b, z2, stats + 1688, N_GRAPHS, 256, 128);
  bn_relu_kernel<<<(N_GRAPHS * 128 + 255) / 256, 256, 0, stream>>>(
      z2, stats + 1688, dn2_gamma, dn2_beta, z2, N_GRAPHS * 128, 128, 1.f / N_GRAPHS);
  final_kernel<<<(N_GRAPHS + 255) / 256, 256, 0, stream>>>(z2, M3, dn3_b, rt_w, rt_b, out);
}